// Round 14
// baseline (287.752 us; speedup 1.0000x reference)
//
#include <hip/hip_runtime.h>
#include <hip/hip_bf16.h>
#include <math.h>

#define THREADS 256
typedef unsigned short ushortT;
typedef __attribute__((ext_vector_type(8))) short bf16x8;   // 8 bf16 = 4 VGPRs
typedef __attribute__((ext_vector_type(4))) float f32x4;

__device__ __forceinline__ void async16(const ushortT* g, ushortT* l) {
  __builtin_amdgcn_global_load_lds(
      (const __attribute__((address_space(1))) unsigned int*)g,
      (__attribute__((address_space(3))) unsigned int*)l, 16, 0, 0);
}

__device__ __forceinline__ ushortT f2bf(float f) {
  __hip_bfloat16 h = __float2bfloat16(f);
  return *reinterpret_cast<ushortT*>(&h);
}

// ---------------------------------------------------------------------------
// Kernel A: fused L2-norm + bf16 convert. ONE WAVE PER ROW (4 rows / block,
// 2048 blocks): no LDS, no __syncthreads, 64-lane shuffle reduce, 4x float4
// per lane (assumes D == 1024, as the rest of the pipeline does).
// ---------------------------------------------------------------------------
__global__ __launch_bounds__(THREADS) void k_prep(const float* __restrict__ x,
                                                  ushortT* __restrict__ xn, int D) {
  const int lane = threadIdx.x & 63;
  const int row = blockIdx.x * 4 + (threadIdx.x >> 6);
  const float4* xr = reinterpret_cast<const float4*>(x) + (size_t)row * (D >> 2);
  float4 v[4];
  float s = 0.f;
  #pragma unroll
  for (int t = 0; t < 4; ++t) {
    v[t] = xr[lane + 64 * t];
    s += v[t].x * v[t].x + v[t].y * v[t].y + v[t].z * v[t].z + v[t].w * v[t].w;
  }
  #pragma unroll
  for (int off = 32; off; off >>= 1) s += __shfl_xor(s, off);
  const float rn = 1.0f / fmaxf(sqrtf(s), 1e-12f);
  ushort4* xo = reinterpret_cast<ushort4*>(xn) + (size_t)row * (D >> 2);
  #pragma unroll
  for (int t = 0; t < 4; ++t) {
    ushort4 o;
    o.x = f2bf(v[t].x * rn); o.y = f2bf(v[t].y * rn);
    o.z = f2bf(v[t].z * rn); o.w = f2bf(v[t].w * rn);
    xo[lane + 64 * t] = o;
  }
}

// ---------------------------------------------------------------------------
// Kernel B: EXACT R9 (verified 169us): triangular 128x128 bf16 MFMA tiles,
// BK=64, 2-barrier loop. Session conclusion: this structure is at its
// staged-byte delivery floor (~24 B/cyc/CU over 1.05 GB); the only path
// below (256² tile, 0.53 GB) spilled in 4/4 configurations (R10-R13).
// partial[(row*NB + cb)*2 + half] = {mp, sp, 0, sn}
// ---------------------------------------------------------------------------
__global__ __launch_bounds__(THREADS, 2) void k_main_mfma(const ushortT* __restrict__ xn,
                                                          const int* __restrict__ tgt,
                                                          float4* __restrict__ partial,
                                                          int D, int nb) {
  __shared__ ushortT Asm[128 * 64];  // 16 KB
  __shared__ ushortT Bsm[128 * 64];  // 16 KB

  const int tid = threadIdx.x;
  const int lane = tid & 63;
  const int w = tid >> 6;

  // --- triangular decode: b -> (bi, bj), bi <= bj
  const int b = blockIdx.x;
  int bi = (int)((2.f * nb + 1.f -
                  sqrtf((2.f * nb + 1.f) * (2.f * nb + 1.f) - 8.f * (float)b)) * 0.5f);
  while ((bi + 1) * (2 * nb - bi) / 2 <= b) ++bi;
  while (bi * (2 * nb - bi + 1) / 2 > b) --bi;
  const int bj = bi + (b - bi * (2 * nb - bi + 1) / 2);
  const bool isdiag = (bi == bj);

  const int i0 = bi * 128, j0 = bj * 128;
  const int wr = (w >> 1) * 64, wc = (w & 1) * 64;

  // --- staging: lane fetches (row = lane&15, chunk = lane>>4) of each 16x32
  // subtile; wave w stages groups w and w+4 of A and B, ksub 0 and 1.
  const int sr = lane & 15, sc = lane >> 4;
  const ushortT* gA0 = xn + (size_t)(i0 + w * 16 + sr) * D + sc * 8;
  const ushortT* gA1 = gA0 + (size_t)64 * D;
  const ushortT* gB0 = xn + (size_t)(j0 + w * 16 + sr) * D + sc * 8;
  const ushortT* gB1 = gB0 + (size_t)64 * D;
  ushortT* lA0 = &Asm[w * 1024];
  ushortT* lA1 = &Asm[(w + 4) * 1024];
  ushortT* lB0 = &Bsm[w * 1024];
  ushortT* lB1 = &Bsm[(w + 4) * 1024];

  const ushortT* Bbase = isdiag ? Asm : Bsm;
  const int aoff = ((w >> 1) * 4) * 1024 + lane * 8;   // ushort index
  const int boff = ((w & 1) * 4) * 1024 + lane * 8;

  f32x4 acc[4][4];
  #pragma unroll
  for (int mt = 0; mt < 4; ++mt)
    #pragma unroll
    for (int nt = 0; nt < 4; ++nt)
      acc[mt][nt] = (f32x4){0.f, 0.f, 0.f, 0.f};

  const int kiters = D / 64;   // 16
  for (int kk = 0; kk < kiters; ++kk) {
    const size_t ko = (size_t)kk * 64;
    async16(gA0 + ko, lA0);
    async16(gA0 + ko + 32, lA0 + 512);
    async16(gA1 + ko, lA1);
    async16(gA1 + ko + 32, lA1 + 512);
    if (!isdiag) {
      async16(gB0 + ko, lB0);
      async16(gB0 + ko + 32, lB0 + 512);
      async16(gB1 + ko, lB1);
      async16(gB1 + ko + 32, lB1 + 512);
    }
    __syncthreads();
    #pragma unroll
    for (int s = 0; s < 2; ++s) {
      bf16x8 afr[4];
      #pragma unroll
      for (int mt = 0; mt < 4; ++mt)
        afr[mt] = *reinterpret_cast<const bf16x8*>(&Asm[aoff + mt * 1024 + s * 512]);
      bf16x8 b0 = *reinterpret_cast<const bf16x8*>(&Bbase[boff + s * 512]);
      bf16x8 b1 = *reinterpret_cast<const bf16x8*>(&Bbase[boff + 1024 + s * 512]);
      #pragma unroll
      for (int mt = 0; mt < 4; ++mt)
        acc[mt][0] = __builtin_amdgcn_mfma_f32_16x16x32_bf16(afr[mt], b0, acc[mt][0], 0, 0, 0);
      #pragma unroll
      for (int mt = 0; mt < 4; ++mt)
        acc[mt][1] = __builtin_amdgcn_mfma_f32_16x16x32_bf16(afr[mt], b1, acc[mt][1], 0, 0, 0);
      b0 = *reinterpret_cast<const bf16x8*>(&Bbase[boff + 2 * 1024 + s * 512]);
      b1 = *reinterpret_cast<const bf16x8*>(&Bbase[boff + 3 * 1024 + s * 512]);
      #pragma unroll
      for (int mt = 0; mt < 4; ++mt)
        acc[mt][2] = __builtin_amdgcn_mfma_f32_16x16x32_bf16(afr[mt], b0, acc[mt][2], 0, 0, 0);
      #pragma unroll
      for (int mt = 0; mt < 4; ++mt)
        acc[mt][3] = __builtin_amdgcn_mfma_f32_16x16x32_bf16(afr[mt], b1, acc[mt][3], 0, 0, 0);
    }
    __syncthreads();
  }

  // --- epilogue. C/D layout: col = lane&15, row = (lane>>4)*4 + reg
  const int q = lane >> 4, c = lane & 15;
  int tj[4];
  #pragma unroll
  for (int nt = 0; nt < 4; ++nt) tj[nt] = tgt[j0 + wc + nt * 16 + c];
  int tir[16];
  #pragma unroll
  for (int mt = 0; mt < 4; ++mt) {
    const int4 t4 = *reinterpret_cast<const int4*>(tgt + i0 + wr + mt * 16 + q * 4);
    tir[mt * 4 + 0] = t4.x; tir[mt * 4 + 1] = t4.y;
    tir[mt * 4 + 2] = t4.z; tir[mt * 4 + 3] = t4.w;
  }

  // orientation 1: rows of bi block, cols of bj block
  #pragma unroll
  for (int mt = 0; mt < 4; ++mt) {
    #pragma unroll
    for (int reg = 0; reg < 4; ++reg) {
      const int i = i0 + wr + mt * 16 + q * 4 + reg;
      const int ti = tir[mt * 4 + reg];
      float m = -1e30f, sn = 0.f;
      float sel[4];
      #pragma unroll
      for (int nt = 0; nt < 4; ++nt) {
        const float s = acc[mt][nt][reg];
        const int j = j0 + wc + nt * 16 + c;
        const bool same = (tj[nt] == ti);
        const bool vpos = same && (j != i);
        const float lp = (fminf(s, 1.25f) - 1.25f) * fmaf(s, 64.f, -48.f);
        const float sv = vpos ? lp : -2e30f;
        sel[nt] = sv;
        m = fmaxf(m, sv);
        const float ln = (fmaxf(s, -0.25f) + 0.25f) * fmaf(s, 64.f, -16.f);
        const float en = __expf(ln);
        sn += same ? 0.f : en;
      }
      #pragma unroll
      for (int off = 1; off < 16; off <<= 1) m = fmaxf(m, __shfl_xor(m, off));
      float sp = 0.f;
      #pragma unroll
      for (int nt = 0; nt < 4; ++nt) sp += __expf(sel[nt] - m);
      #pragma unroll
      for (int off = 1; off < 16; off <<= 1) {
        sp += __shfl_xor(sp, off);
        sn += __shfl_xor(sn, off);
      }
      if (c == 0) {
        float4 o; o.x = m; o.y = sp; o.z = 0.f; o.w = sn;
        partial[((size_t)i * nb + bj) * 2 + (w & 1)] = o;
      }
    }
  }

  // orientation 2: rows of bj block, cols of bi block (off-diagonal only).
  if (!isdiag) {
    #pragma unroll
    for (int nt = 0; nt < 4; ++nt) {
      const int jt = tj[nt];
      const int jrow = j0 + wc + nt * 16 + c;
      float m = -1e30f, sn = 0.f;
      #pragma unroll
      for (int mt = 0; mt < 4; ++mt) {
        #pragma unroll
        for (int reg = 0; reg < 4; ++reg) {
          const float s = acc[mt][nt][reg];
          const bool same = (tir[mt * 4 + reg] == jt);  // j != i guaranteed off-diag
          const float lp = (fminf(s, 1.25f) - 1.25f) * fmaf(s, 64.f, -48.f);
          m = fmaxf(m, same ? lp : -2e30f);
          const float ln = (fmaxf(s, -0.25f) + 0.25f) * fmaf(s, 64.f, -16.f);
          const float en = __expf(ln);
          sn += same ? 0.f : en;
        }
      }
      m = fmaxf(m, __shfl_xor(m, 16));
      m = fmaxf(m, __shfl_xor(m, 32));
      float sp = 0.f;
      #pragma unroll
      for (int mt = 0; mt < 4; ++mt) {
        #pragma unroll
        for (int reg = 0; reg < 4; ++reg) {
          const float s = acc[mt][nt][reg];
          const bool same = (tir[mt * 4 + reg] == jt);
          const float lp = (fminf(s, 1.25f) - 1.25f) * fmaf(s, 64.f, -48.f);
          sp += __expf((same ? lp : -2e30f) - m);
        }
      }
      sp += __shfl_xor(sp, 16); sp += __shfl_xor(sp, 32);
      sn += __shfl_xor(sn, 16); sn += __shfl_xor(sn, 32);
      if (lane < 16) {
        float4 o; o.x = m; o.y = sp; o.z = 0.f; o.w = sn;
        partial[((size_t)jrow * nb + bi) * 2 + (w >> 1)] = o;
      }
    }
  }
}

// ---------------------------------------------------------------------------
// Kernel C: fold 128 partials per row -> row loss, then ONE atomicAdd pair
// per block into acc[0]=sum, acc[1]=count (row_loss array eliminated).
// ---------------------------------------------------------------------------
__global__ __launch_bounds__(THREADS) void k_reduce(const float4* __restrict__ partial,
                                                    float* __restrict__ acc) {
  __shared__ float ssum[4];
  __shared__ float scnt[4];
  const int lane = threadIdx.x & 63;
  const int wv = threadIdx.x >> 6;
  const int row = blockIdx.x * 4 + wv;
  const float4 a = partial[(size_t)row * 128 + lane];
  const float4 b = partial[(size_t)row * 128 + 64 + lane];
  float mp = fmaxf(a.x, b.x);
  float sp = a.y * __expf(a.x - mp) + b.y * __expf(b.x - mp);
  float sn = a.w + b.w;
  #pragma unroll
  for (int off = 1; off < 64; off <<= 1) {
    const float m2 = __shfl_xor(mp, off), s2 = __shfl_xor(sp, off);
    const float nm = fmaxf(mp, m2);
    sp = sp * __expf(mp - nm) + s2 * __expf(m2 - nm);
    mp = nm;
    sn += __shfl_xor(sn, off);
  }
  if (lane == 0) {
    float loss = 0.f, cnt = 0.f;
    if (sp > 0.f && sn > 0.f) {
      const float z = mp + logf(sp) + logf(sn);
      loss = (z > 0.f) ? (z + log1pf(__expf(-z))) : log1pf(__expf(z));
      cnt = 1.f;
    }
    ssum[wv] = loss; scnt[wv] = cnt;
  }
  __syncthreads();
  if (threadIdx.x == 0) {
    atomicAdd(&acc[0], ssum[0] + ssum[1] + ssum[2] + ssum[3]);
    atomicAdd(&acc[1], scnt[0] + scnt[1] + scnt[2] + scnt[3]);
  }
}

// ---------------------------------------------------------------------------
// Kernel D: trivial division.
// ---------------------------------------------------------------------------
__global__ void k_final(const float* __restrict__ acc, float* __restrict__ out) {
  if (threadIdx.x == 0) out[0] = acc[0] / fmaxf(acc[1], 1.f);
}

// ---------------------------------------------------------------------------
extern "C" void kernel_launch(void* const* d_in, const int* in_sizes, int n_in,
                              void* d_out, int out_size, void* d_ws, size_t ws_size,
                              hipStream_t stream) {
  const float* x = (const float*)d_in[0];
  const int* tgt = (const int*)d_in[1];
  float* out = (float*)d_out;
  const int B = in_sizes[1];
  const int D = in_sizes[0] / B;
  const int nb = B / 128;

  ushortT* xn = (ushortT*)d_ws;                                   // B*D bf16 (16 MB)
  float4* partial = (float4*)((char*)d_ws + (size_t)B * D * 2);   // B*2*nb float4 (16 MB)
  float* acc = (float*)((char*)d_ws + (size_t)B * D * 2 + (size_t)B * 2 * nb * 16);

  hipMemsetAsync(acc, 0, 2 * sizeof(float), stream);
  k_prep<<<B / 4, THREADS, 0, stream>>>(x, xn, D);
  k_main_mfma<<<nb * (nb + 1) / 2, THREADS, 0, stream>>>(xn, tgt, partial, D, nb);
  k_reduce<<<B / 4, THREADS, 0, stream>>>(partial, acc);
  k_final<<<1, 64, 0, stream>>>(acc, out);
}

// Round 15
// 245.319 us; speedup vs baseline: 1.1730x; 1.1730x over previous
//
#include <hip/hip_runtime.h>
#include <hip/hip_bf16.h>
#include <math.h>

#define THREADS 256
typedef unsigned short ushortT;
typedef __attribute__((ext_vector_type(8))) short bf16x8;   // 8 bf16 = 4 VGPRs
typedef __attribute__((ext_vector_type(4))) float f32x4;

__device__ __forceinline__ void async16(const ushortT* g, ushortT* l) {
  __builtin_amdgcn_global_load_lds(
      (const __attribute__((address_space(1))) unsigned int*)g,
      (__attribute__((address_space(3))) unsigned int*)l, 16, 0, 0);
}

__device__ __forceinline__ ushortT f2bf(float f) {
  __hip_bfloat16 h = __float2bfloat16(f);
  return *reinterpret_cast<ushortT*>(&h);
}

// ---------------------------------------------------------------------------
// Kernel A: fused L2-norm + bf16 convert. One block per row (256 thr x float4).
// ---------------------------------------------------------------------------
__global__ __launch_bounds__(THREADS) void k_prep(const float* __restrict__ x,
                                                  ushortT* __restrict__ xn, int D) {
  __shared__ float red[4];
  const int row = blockIdx.x;
  const int tid = threadIdx.x;
  const int gid = row * (D / 4) + tid;
  const float4 v = reinterpret_cast<const float4*>(x)[gid];
  float s = v.x * v.x + v.y * v.y + v.z * v.z + v.w * v.w;
  #pragma unroll
  for (int off = 32; off; off >>= 1) s += __shfl_xor(s, off);
  if ((tid & 63) == 0) red[tid >> 6] = s;
  __syncthreads();
  const float tot = red[0] + red[1] + red[2] + red[3];
  const float rn = 1.0f / fmaxf(sqrtf(tot), 1e-12f);
  ushort4 o;
  o.x = f2bf(v.x * rn); o.y = f2bf(v.y * rn);
  o.z = f2bf(v.z * rn); o.w = f2bf(v.w * rn);
  reinterpret_cast<ushort4*>(xn)[gid] = o;
}

// ---------------------------------------------------------------------------
// Kernel B: triangular 128x128 bf16 MFMA tiles + dual-orientation circle-loss
// epilogue. Block b -> (bi <= bj). Grid = nb(nb+1)/2 = 2080 blocks (nb=64).
// BK=64: 16 K-iters; per iter each wave does 2 sub-steps x 16 MFMA = 32 MFMA
// against one barrier drain; 8 async16/wave/iter (4 on diag); LDS 2x16KB.
// Session conclusion (R0-R14): this is the staged-byte delivery floor
// (1.05 GB @ ~24 B/cyc/CU = ~169us). 256² (0.53 GB) spills in all 4 tested
// register configurations; all schedule-level levers neutral-to-negative.
// partial[(row*NB + cb)*2 + half] = {mp, sp, 0, sn}
// ---------------------------------------------------------------------------
__global__ __launch_bounds__(THREADS, 2) void k_main_mfma(const ushortT* __restrict__ xn,
                                                          const int* __restrict__ tgt,
                                                          float4* __restrict__ partial,
                                                          int D, int nb) {
  __shared__ ushortT Asm[128 * 64];  // 16 KB
  __shared__ ushortT Bsm[128 * 64];  // 16 KB

  const int tid = threadIdx.x;
  const int lane = tid & 63;
  const int w = tid >> 6;

  // --- triangular decode: b -> (bi, bj), bi <= bj
  const int b = blockIdx.x;
  int bi = (int)((2.f * nb + 1.f -
                  sqrtf((2.f * nb + 1.f) * (2.f * nb + 1.f) - 8.f * (float)b)) * 0.5f);
  while ((bi + 1) * (2 * nb - bi) / 2 <= b) ++bi;
  while (bi * (2 * nb - bi + 1) / 2 > b) --bi;
  const int bj = bi + (b - bi * (2 * nb - bi + 1) / 2);
  const bool isdiag = (bi == bj);

  const int i0 = bi * 128, j0 = bj * 128;
  const int wr = (w >> 1) * 64, wc = (w & 1) * 64;

  // --- staging: lane fetches (row = lane&15, chunk = lane>>4) of each 16x32
  // subtile; wave w stages groups w and w+4 of A and B, ksub 0 and 1.
  const int sr = lane & 15, sc = lane >> 4;
  const ushortT* gA0 = xn + (size_t)(i0 + w * 16 + sr) * D + sc * 8;
  const ushortT* gA1 = gA0 + (size_t)64 * D;
  const ushortT* gB0 = xn + (size_t)(j0 + w * 16 + sr) * D + sc * 8;
  const ushortT* gB1 = gB0 + (size_t)64 * D;
  ushortT* lA0 = &Asm[w * 1024];
  ushortT* lA1 = &Asm[(w + 4) * 1024];
  ushortT* lB0 = &Bsm[w * 1024];
  ushortT* lB1 = &Bsm[(w + 4) * 1024];

  const ushortT* Bbase = isdiag ? Asm : Bsm;
  const int aoff = ((w >> 1) * 4) * 1024 + lane * 8;   // ushort index
  const int boff = ((w & 1) * 4) * 1024 + lane * 8;

  f32x4 acc[4][4];
  #pragma unroll
  for (int mt = 0; mt < 4; ++mt)
    #pragma unroll
    for (int nt = 0; nt < 4; ++nt)
      acc[mt][nt] = (f32x4){0.f, 0.f, 0.f, 0.f};

  const int kiters = D / 64;   // 16
  for (int kk = 0; kk < kiters; ++kk) {
    const size_t ko = (size_t)kk * 64;
    async16(gA0 + ko, lA0);
    async16(gA0 + ko + 32, lA0 + 512);
    async16(gA1 + ko, lA1);
    async16(gA1 + ko + 32, lA1 + 512);
    if (!isdiag) {
      async16(gB0 + ko, lB0);
      async16(gB0 + ko + 32, lB0 + 512);
      async16(gB1 + ko, lB1);
      async16(gB1 + ko + 32, lB1 + 512);
    }
    __syncthreads();
    #pragma unroll
    for (int s = 0; s < 2; ++s) {
      bf16x8 afr[4];
      #pragma unroll
      for (int mt = 0; mt < 4; ++mt)
        afr[mt] = *reinterpret_cast<const bf16x8*>(&Asm[aoff + mt * 1024 + s * 512]);
      bf16x8 b0 = *reinterpret_cast<const bf16x8*>(&Bbase[boff + s * 512]);
      bf16x8 b1 = *reinterpret_cast<const bf16x8*>(&Bbase[boff + 1024 + s * 512]);
      #pragma unroll
      for (int mt = 0; mt < 4; ++mt)
        acc[mt][0] = __builtin_amdgcn_mfma_f32_16x16x32_bf16(afr[mt], b0, acc[mt][0], 0, 0, 0);
      #pragma unroll
      for (int mt = 0; mt < 4; ++mt)
        acc[mt][1] = __builtin_amdgcn_mfma_f32_16x16x32_bf16(afr[mt], b1, acc[mt][1], 0, 0, 0);
      b0 = *reinterpret_cast<const bf16x8*>(&Bbase[boff + 2 * 1024 + s * 512]);
      b1 = *reinterpret_cast<const bf16x8*>(&Bbase[boff + 3 * 1024 + s * 512]);
      #pragma unroll
      for (int mt = 0; mt < 4; ++mt)
        acc[mt][2] = __builtin_amdgcn_mfma_f32_16x16x32_bf16(afr[mt], b0, acc[mt][2], 0, 0, 0);
      #pragma unroll
      for (int mt = 0; mt < 4; ++mt)
        acc[mt][3] = __builtin_amdgcn_mfma_f32_16x16x32_bf16(afr[mt], b1, acc[mt][3], 0, 0, 0);
    }
    __syncthreads();
  }

  // --- epilogue. C/D layout: col = lane&15, row = (lane>>4)*4 + reg
  const int q = lane >> 4, c = lane & 15;
  int tj[4];
  #pragma unroll
  for (int nt = 0; nt < 4; ++nt) tj[nt] = tgt[j0 + wc + nt * 16 + c];
  int tir[16];
  #pragma unroll
  for (int mt = 0; mt < 4; ++mt) {
    const int4 t4 = *reinterpret_cast<const int4*>(tgt + i0 + wr + mt * 16 + q * 4);
    tir[mt * 4 + 0] = t4.x; tir[mt * 4 + 1] = t4.y;
    tir[mt * 4 + 2] = t4.z; tir[mt * 4 + 3] = t4.w;
  }

  // orientation 1: rows of bi block, cols of bj block
  #pragma unroll
  for (int mt = 0; mt < 4; ++mt) {
    #pragma unroll
    for (int reg = 0; reg < 4; ++reg) {
      const int i = i0 + wr + mt * 16 + q * 4 + reg;
      const int ti = tir[mt * 4 + reg];
      float m = -1e30f, sn = 0.f;
      float sel[4];
      #pragma unroll
      for (int nt = 0; nt < 4; ++nt) {
        const float s = acc[mt][nt][reg];
        const int j = j0 + wc + nt * 16 + c;
        const bool same = (tj[nt] == ti);
        const bool vpos = same && (j != i);
        const float lp = (fminf(s, 1.25f) - 1.25f) * fmaf(s, 64.f, -48.f);
        const float sv = vpos ? lp : -2e30f;
        sel[nt] = sv;
        m = fmaxf(m, sv);
        const float ln = (fmaxf(s, -0.25f) + 0.25f) * fmaf(s, 64.f, -16.f);
        const float en = __expf(ln);
        sn += same ? 0.f : en;
      }
      #pragma unroll
      for (int off = 1; off < 16; off <<= 1) m = fmaxf(m, __shfl_xor(m, off));
      float sp = 0.f;
      #pragma unroll
      for (int nt = 0; nt < 4; ++nt) sp += __expf(sel[nt] - m);
      #pragma unroll
      for (int off = 1; off < 16; off <<= 1) {
        sp += __shfl_xor(sp, off);
        sn += __shfl_xor(sn, off);
      }
      if (c == 0) {
        float4 o; o.x = m; o.y = sp; o.z = 0.f; o.w = sn;
        partial[((size_t)i * nb + bj) * 2 + (w & 1)] = o;
      }
    }
  }

  // orientation 2: rows of bj block, cols of bi block (off-diagonal only).
  if (!isdiag) {
    #pragma unroll
    for (int nt = 0; nt < 4; ++nt) {
      const int jt = tj[nt];
      const int jrow = j0 + wc + nt * 16 + c;
      float m = -1e30f, sn = 0.f;
      #pragma unroll
      for (int mt = 0; mt < 4; ++mt) {
        #pragma unroll
        for (int reg = 0; reg < 4; ++reg) {
          const float s = acc[mt][nt][reg];
          const bool same = (tir[mt * 4 + reg] == jt);  // j != i guaranteed off-diag
          const float lp = (fminf(s, 1.25f) - 1.25f) * fmaf(s, 64.f, -48.f);
          m = fmaxf(m, same ? lp : -2e30f);
          const float ln = (fmaxf(s, -0.25f) + 0.25f) * fmaf(s, 64.f, -16.f);
          const float en = __expf(ln);
          sn += same ? 0.f : en;
        }
      }
      m = fmaxf(m, __shfl_xor(m, 16));
      m = fmaxf(m, __shfl_xor(m, 32));
      float sp = 0.f;
      #pragma unroll
      for (int mt = 0; mt < 4; ++mt) {
        #pragma unroll
        for (int reg = 0; reg < 4; ++reg) {
          const float s = acc[mt][nt][reg];
          const bool same = (tir[mt * 4 + reg] == jt);
          const float lp = (fminf(s, 1.25f) - 1.25f) * fmaf(s, 64.f, -48.f);
          sp += __expf((same ? lp : -2e30f) - m);
        }
      }
      sp += __shfl_xor(sp, 16); sp += __shfl_xor(sp, 32);
      sn += __shfl_xor(sn, 16); sn += __shfl_xor(sn, 32);
      if (lane < 16) {
        float4 o; o.x = m; o.y = sp; o.z = 0.f; o.w = sn;
        partial[((size_t)jrow * nb + bi) * 2 + (w >> 1)] = o;
      }
    }
  }
}

// ---------------------------------------------------------------------------
// Kernel C: fold 128 partials per row -> row loss. One wave per row.
// ---------------------------------------------------------------------------
__global__ __launch_bounds__(THREADS) void k_reduce(const float4* __restrict__ partial,
                                                    float* __restrict__ row_loss) {
  const int lane = threadIdx.x & 63;
  const int row = blockIdx.x * 4 + (threadIdx.x >> 6);
  const float4 a = partial[(size_t)row * 128 + lane];
  const float4 b = partial[(size_t)row * 128 + 64 + lane];
  float mp = fmaxf(a.x, b.x);
  float sp = a.y * __expf(a.x - mp) + b.y * __expf(b.x - mp);
  float sn = a.w + b.w;
  #pragma unroll
  for (int off = 1; off < 64; off <<= 1) {
    const float m2 = __shfl_xor(mp, off), s2 = __shfl_xor(sp, off);
    const float nm = fmaxf(mp, m2);
    sp = sp * __expf(mp - nm) + s2 * __expf(m2 - nm);
    mp = nm;
    sn += __shfl_xor(sn, off);
  }
  if (lane == 0) {
    float loss = -1.0f;
    if (sp > 0.f && sn > 0.f) {
      const float z = mp + logf(sp) + logf(sn);
      loss = (z > 0.f) ? (z + log1pf(__expf(-z))) : log1pf(__expf(z));
    }
    row_loss[row] = loss;
  }
}

// ---------------------------------------------------------------------------
// Kernel D: masked mean over rows. One block.
// ---------------------------------------------------------------------------
__global__ __launch_bounds__(THREADS) void k_final(const float* __restrict__ row_loss,
                                                   float* __restrict__ out, int B) {
  __shared__ float ssum[4];
  __shared__ float scnt[4];
  const int tid = threadIdx.x;
  float sum = 0.f, cnt = 0.f;
  for (int i = tid; i < B; i += THREADS) {
    const float l = row_loss[i];
    if (l >= 0.f) { sum += l; cnt += 1.f; }
  }
  #pragma unroll
  for (int off = 32; off; off >>= 1) {
    sum += __shfl_xor(sum, off);
    cnt += __shfl_xor(cnt, off);
  }
  if ((tid & 63) == 0) { ssum[tid >> 6] = sum; scnt[tid >> 6] = cnt; }
  __syncthreads();
  if (tid == 0) {
    float ts = 0.f, tc = 0.f;
    #pragma unroll
    for (int w = 0; w < 4; ++w) { ts += ssum[w]; tc += scnt[w]; }
    out[0] = ts / fmaxf(tc, 1.f);
  }
}

// ---------------------------------------------------------------------------
extern "C" void kernel_launch(void* const* d_in, const int* in_sizes, int n_in,
                              void* d_out, int out_size, void* d_ws, size_t ws_size,
                              hipStream_t stream) {
  const float* x = (const float*)d_in[0];
  const int* tgt = (const int*)d_in[1];
  float* out = (float*)d_out;
  const int B = in_sizes[1];
  const int D = in_sizes[0] / B;
  const int nb = B / 128;

  ushortT* xn = (ushortT*)d_ws;                                   // B*D bf16 (16 MB)
  float4* partial = (float4*)((char*)d_ws + (size_t)B * D * 2);   // B*2*nb float4 (16 MB)
  float* row_loss = (float*)((char*)d_ws + (size_t)B * D * 2 + (size_t)B * 2 * nb * 16);

  k_prep<<<B, THREADS, 0, stream>>>(x, xn, D);
  k_main_mfma<<<nb * (nb + 1) / 2, THREADS, 0, stream>>>(xn, tgt, partial, D, nb);
  k_reduce<<<B / 4, THREADS, 0, stream>>>(partial, row_loss);
  k_final<<<1, THREADS, 0, stream>>>(row_loss, out, B);
}